// Round 1
// baseline (290.886 us; speedup 1.0000x reference)
//
#include <hip/hip_runtime.h>

// Problem: conv(3x3,C3->F32) -> earlyMLP(32768->128) -> reset-masked LSTM(128) -> outMLP(128->128)
// Key tricks:
//  1) conv folded into early MLP: U[3072,128] = fold(conv_w, early_w)  => GEMM K=3072 not 32768 (10.7x FLOPs)
//  2) done-resets (p=0.5) split the scan into ~500 independent segments => segment-parallel LSTM
// ws usage ~10.2 MB.

typedef unsigned short ushort_t;
typedef short bf16x8 __attribute__((ext_vector_type(8)));
typedef float f32x4 __attribute__((ext_vector_type(4)));

__device__ __forceinline__ ushort_t f2b(float f) {
  unsigned int u = __float_as_uint(f);
  unsigned int r = (u + 0x7fffu + ((u >> 16) & 1u)) >> 16;  // RNE
  return (ushort_t)r;
}

#define NT   1024   // N*T frames
#define KIN  3072   // H*W*C
#define HID_ 128
#define GATE 512

// ---------------- prep: casts/transposes + bias2 init ----------------
__global__ __launch_bounds__(256) void prep_kernel(
    const float* __restrict__ x, const float* __restrict__ wx,
    const float* __restrict__ wh, const float* __restrict__ ow,
    const float* __restrict__ eb,
    ushort_t* __restrict__ xb, ushort_t* __restrict__ wxT,
    float* __restrict__ whTf, ushort_t* __restrict__ owT,
    float* __restrict__ bias2)
{
  const int XE = NT * KIN;                       // 3145728
  const int total = XE + 65536 + 65536 + 16384 + 128;
  for (int i = blockIdx.x * blockDim.x + threadIdx.x; i < total;
       i += gridDim.x * blockDim.x) {
    if (i < XE) { xb[i] = f2b(x[i]); continue; }
    int j = i - XE;
    if (j < 65536) { int n = j >> 7, k = j & 127; wxT[j] = f2b(wx[k * 512 + n]); continue; }
    j -= 65536;
    if (j < 65536) { int n = j >> 7, k = j & 127; whTf[j] = wh[k * 512 + n]; continue; }
    j -= 65536;
    if (j < 16384) { int n = j >> 7, k = j & 127; owT[j] = f2b(ow[k * 128 + n]); continue; }
    j -= 16384;
    bias2[j] = eb[j];                            // conv_b term atomically added by build_u
  }
}

// ---------------- build U: fold conv into early MLP ----------------
// U[(h',w')*3+c][o] = sum_{kh,kw valid} conv_w[kh,kw,c,:] . early_w[((h'-kh+1)*32+(w'-kw+1))*32+:, o]
// stored transposed bf16: UT[o][k'] for the GEMM's BT operand.
__global__ __launch_bounds__(128) void build_u(
    const float* __restrict__ conv_w, const float* __restrict__ conv_b,
    const float* __restrict__ early_w,
    ushort_t* __restrict__ UT, float* __restrict__ bias2)
{
  __shared__ float cw[864];                      // [kh][kw][c][f]
  const int tid = threadIdx.x;                   // = o
  const int p = blockIdx.x;                      // input pixel p' = (h',w')
  for (int i = tid; i < 864; i += 128) cw[i] = conv_w[i];
  __syncthreads();
  const int hp = p >> 5, wp = p & 31;
  float a0 = 0.f, a1 = 0.f, a2 = 0.f;
  for (int kh = 0; kh < 3; kh++) {
    int h = hp - kh + 1; if ((unsigned)h >= 32u) continue;
    for (int kw = 0; kw < 3; kw++) {
      int w = wp - kw + 1; if ((unsigned)w >= 32u) continue;
      const float* wr = early_w + ((size_t)((h * 32 + w) * 32)) * 128 + tid;
      const float* cwp = cw + (kh * 3 + kw) * 96;
      #pragma unroll 8
      for (int f = 0; f < 32; f++) {
        float wv = wr[f * 128];
        a0 += cwp[f]      * wv;
        a1 += cwp[32 + f] * wv;
        a2 += cwp[64 + f] * wv;
      }
    }
  }
  size_t ub = (size_t)tid * KIN + p * 3;
  UT[ub + 0] = f2b(a0); UT[ub + 1] = f2b(a1); UT[ub + 2] = f2b(a2);

  // conv_b contribution to bias2 (zeros in this problem, kept for generality)
  if (p < 32) {
    float part = 0.f;
    for (int pp = p * 32; pp < p * 32 + 32; pp++)
      for (int f = 0; f < 32; f++)
        part += conv_b[f] * early_w[(size_t)(pp * 32 + f) * 128 + tid];
    atomicAdd(&bias2[tid], part);
  }
}

// ---------------- generic bf16 MFMA GEMM: out = act(A @ BT^T + bias) ----------------
// A [M][K] bf16, BT [N][K] bf16, tile M16 x N128 x K64, 4 waves (each 2 N-subtiles).
__global__ __launch_bounds__(256) void gemm_bf16(
    const ushort_t* __restrict__ A, const ushort_t* __restrict__ BT,
    const float* __restrict__ bias,
    float* __restrict__ outf, ushort_t* __restrict__ outb,
    int M, int N, int K, int relu)
{
  __shared__ short As[16 * 72];    // rows padded 64->72 elems (16B) to break bank conflicts
  __shared__ short Bs[128 * 72];
  const int tid = threadIdx.x;
  const int m0 = blockIdx.x * 16;
  const int n0 = blockIdx.y * 128;
  const int wave = tid >> 6, lane = tid & 63;
  const int quad = lane >> 4, l15 = lane & 15;
  const int c0 = wave * 32;

  f32x4 acc0 = {0.f, 0.f, 0.f, 0.f};
  f32x4 acc1 = {0.f, 0.f, 0.f, 0.f};

  for (int k0 = 0; k0 < K; k0 += 64) {
    __syncthreads();
    for (int s = tid; s < 1152; s += 256) {      // 128 A-slots + 1024 B-slots of 16B
      if (s < 128) {
        int row = s >> 3, t8 = s & 7;
        const uint4* g = (const uint4*)(A + (size_t)(m0 + row) * K + k0 + t8 * 8);
        *(uint4*)&As[row * 72 + t8 * 8] = *g;
      } else {
        int s2 = s - 128;
        int row = s2 >> 3, t8 = s2 & 7;
        const uint4* g = (const uint4*)(BT + (size_t)(n0 + row) * K + k0 + t8 * 8);
        *(uint4*)&Bs[row * 72 + t8 * 8] = *g;
      }
    }
    __syncthreads();
    #pragma unroll
    for (int ks = 0; ks < 2; ks++) {
      int ko = ks * 32 + quad * 8;               // A[m=l15][k=quad*8+j] layout (m120-verified)
      bf16x8 a  = *(const bf16x8*)&As[l15 * 72 + ko];
      bf16x8 b0 = *(const bf16x8*)&Bs[(c0 + l15) * 72 + ko];
      bf16x8 b1 = *(const bf16x8*)&Bs[(c0 + 16 + l15) * 72 + ko];
      acc0 = __builtin_amdgcn_mfma_f32_16x16x32_bf16(a, b0, acc0, 0, 0, 0);
      acc1 = __builtin_amdgcn_mfma_f32_16x16x32_bf16(a, b1, acc1, 0, 0, 0);
    }
  }

  // C/D: col = lane&15, row = quad*4 + reg  (m89/m91-verified)
  #pragma unroll
  for (int r = 0; r < 4; r++) {
    int m = m0 + quad * 4 + r;
    int n1 = n0 + c0 + l15;
    int n2 = n1 + 16;
    float v1 = acc0[r] + bias[n1];
    float v2 = acc1[r] + bias[n2];
    if (relu) { v1 = fmaxf(v1, 0.f); v2 = fmaxf(v2, 0.f); }
    size_t o1 = (size_t)m * N + n1, o2 = (size_t)m * N + n2;
    if (outf) { outf[o1] = v1; outf[o2] = v2; }
    if (outb) { outb[o1] = f2b(v1); outb[o2] = f2b(v2); }
  }
}

// ---------------- segment-parallel LSTM ----------------
__device__ __forceinline__ float fsig(float x) {
  return 1.f / (1.f + exp2f(-1.44269504f * x));
}
__device__ __forceinline__ float ftanh(float x) {
  float e = exp2f(2.885390082f * x);             // exp(2x)
  return 1.f - 2.f / (e + 1.f);
}
__device__ __forceinline__ int nth_bit(unsigned long long m0, unsigned long long m1, int i) {
  int c0 = __popcll(m0);
  if (i < c0) {
    unsigned long long m = m0;
    for (int k = 0; k < i; k++) m &= m - 1;
    return __ffsll((long long)m) - 1;
  }
  i -= c0;
  unsigned long long m = m1;
  for (int k = 0; k < i; k++) m &= m - 1;
  return 64 + __ffsll((long long)m) - 1;
}

// 512 threads: thread j owns gate-column j; Wh column (128 f32) lives in registers.
__global__ __launch_bounds__(512, 2) void lstm_scan(
    const int* __restrict__ done, const float* __restrict__ zx,
    const float* __restrict__ whTf, ushort_t* __restrict__ hsb,
    float* __restrict__ dout)
{
  __shared__ float z_s[512];
  __shared__ float h_s[128];
  __shared__ float c_s[128];
  __shared__ unsigned long long masks[16];       // [n][2] segment-start bitmasks
  const int tid = threadIdx.x;

  float w[128];                                  // Wh[:, tid] in VGPRs
  {
    const float4* wp = (const float4*)(whTf + (size_t)tid * 128);
    #pragma unroll
    for (int o = 0; o < 32; o++) {
      float4 v = wp[o];
      w[4*o+0] = v.x; w[4*o+1] = v.y; w[4*o+2] = v.z; w[4*o+3] = v.w;
    }
  }

  // segment discovery: start at t==0 or done[n][t]!=0
  for (int n = 0; n < 8; n++) {
    bool flag = false;
    if (tid < 128) flag = (tid == 0) || (done[n * 128 + tid] != 0);
    unsigned long long m = __ballot(flag);
    if (tid == 0)  masks[2*n]     = m;           // t 0..63
    if (tid == 64) masks[2*n + 1] = m;           // t 64..127
  }
  __syncthreads();

  int total = 0;
  #pragma unroll
  for (int n = 0; n < 8; n++)
    total += __popcll(masks[2*n]) + __popcll(masks[2*n+1]);

  for (int g = blockIdx.x; g < total; g += gridDim.x) {
    int i = g, n = 0, cn = 0;
    for (; n < 8; n++) {
      cn = __popcll(masks[2*n]) + __popcll(masks[2*n+1]);
      if (i < cn) break;
      i -= cn;
    }
    int t0 = nth_bit(masks[2*n], masks[2*n+1], i);
    int t1 = (i + 1 < cn) ? nth_bit(masks[2*n], masks[2*n+1], i + 1) : 128;

    if (tid < 128) { h_s[tid] = 0.f; c_s[tid] = 0.f; }
    __syncthreads();

    for (int t = t0; t < t1; t++) {
      float zval = zx[((size_t)n * 128 + t) * 512 + tid];
      float a0 = 0.f, a1 = 0.f, a2 = 0.f, a3 = 0.f;
      #pragma unroll
      for (int o = 0; o < 32; o++) {
        float4 hv = *(const float4*)&h_s[4 * o]; // LDS broadcast, conflict-free
        a0 += w[4*o+0] * hv.x;
        a1 += w[4*o+1] * hv.y;
        a2 += w[4*o+2] * hv.z;
        a3 += w[4*o+3] * hv.w;
      }
      z_s[tid] = zval + (a0 + a1) + (a2 + a3);
      __syncthreads();
      if (tid < 128) {
        float ig = fsig(z_s[tid]);
        float fg = fsig(z_s[tid + 128]);
        float gg = ftanh(z_s[tid + 256]);
        float og = fsig(z_s[tid + 384]);
        float c = fg * c_s[tid] + ig * gg;
        float hn = og * ftanh(c);
        c_s[tid] = c; h_s[tid] = hn;
        hsb[((size_t)n * 128 + t) * 128 + tid] = f2b(hn);
        if (t == 127) {                           // final state of the sequence
          dout[n * 128 + tid] = c;
          dout[1024 + n * 128 + tid] = hn;
        }
      }
      __syncthreads();
    }
  }
}

// ---------------- launch ----------------
extern "C" void kernel_launch(void* const* d_in, const int* in_sizes, int n_in,
                              void* d_out, int out_size, void* d_ws, size_t ws_size,
                              hipStream_t stream) {
  const float* x       = (const float*)d_in[0];
  const int*   done    = (const int*)  d_in[1];
  const float* conv_w  = (const float*)d_in[2];
  const float* conv_b  = (const float*)d_in[3];
  const float* early_w = (const float*)d_in[4];
  const float* early_b = (const float*)d_in[5];
  const float* lstm_wx = (const float*)d_in[6];
  const float* lstm_wh = (const float*)d_in[7];
  const float* lstm_b  = (const float*)d_in[8];
  const float* out_w   = (const float*)d_in[9];
  const float* out_b   = (const float*)d_in[10];
  float* dout = (float*)d_out;                   // [c_fin 1024][h_fin 1024][y 131072]

  char* ws = (char*)d_ws;
  ushort_t* xb    = (ushort_t*)(ws + 0);         // [1024][3072] bf16
  ushort_t* UT    = (ushort_t*)(ws + 6291456);   // [128][3072]  bf16 (B^T for feat GEMM)
  ushort_t* featb = (ushort_t*)(ws + 7077888);   // [1024][128]  bf16
  float*    zx    = (float*)   (ws + 7340032);   // [1024][512]  f32
  ushort_t* wxT   = (ushort_t*)(ws + 9437184);   // [512][128]   bf16
  float*    whTf  = (float*)   (ws + 9568256);   // [512][128]   f32 (transposed Wh)
  ushort_t* owT   = (ushort_t*)(ws + 9830400);   // [128][128]   bf16
  ushort_t* hsb   = (ushort_t*)(ws + 9863168);   // [1024][128]  bf16
  float*    bias2 = (float*)   (ws + 10125312);  // [128]        f32

  // 1) casts/transposes + bias2 = early_b
  prep_kernel<<<2048, 256, 0, stream>>>(x, lstm_wx, lstm_wh, out_w, early_b,
                                        xb, wxT, whTf, owT, bias2);
  // 2) fold conv into U (+ conv_b term into bias2)
  build_u<<<1024, 128, 0, stream>>>(conv_w, conv_b, early_w, UT, bias2);
  // 3) feat = relu(x @ U + bias2)            [1024,3072]@[3072,128]
  gemm_bf16<<<dim3(64, 1), 256, 0, stream>>>(xb, UT, bias2, nullptr, featb,
                                             1024, 128, 3072, 1);
  // 4) zx = feat @ Wx + lstm_b               [1024,128]@[128,512]
  gemm_bf16<<<dim3(64, 4), 256, 0, stream>>>(featb, wxT, lstm_b, zx, nullptr,
                                             1024, 512, 128, 0);
  // 5) segment-parallel masked LSTM
  lstm_scan<<<64, 512, 0, stream>>>(done, zx, whTf, hsb, dout);
  // 6) y = relu(hs @ out_w + out_b)          [1024,128]@[128,128]
  gemm_bf16<<<dim3(64, 1), 256, 0, stream>>>(hsb, owT, out_b, dout + 2048, nullptr,
                                             1024, 128, 128, 1);
}

// Round 2
// 187.376 us; speedup vs baseline: 1.5524x; 1.5524x over previous
//
#include <hip/hip_runtime.h>

// conv(3x3,C3->F32) -> earlyMLP(32768->128) -> reset-masked LSTM(128) -> outMLP(128->128)
// R1: feat GEMM was 103us latency-bound (64 blocks, occ 2.7%). Now split-K x8 (512 blocks)
//     + f32->bf16 cast fused into staging; small GEMMs re-tiled to K=128 single-shot.

typedef unsigned short ushort_t;
typedef short bf16x8 __attribute__((ext_vector_type(8)));
typedef float f32x4 __attribute__((ext_vector_type(4)));

__device__ __forceinline__ ushort_t f2b(float f) {
  unsigned int u = __float_as_uint(f);
  unsigned int r = (u + 0x7fffu + ((u >> 16) & 1u)) >> 16;  // RNE
  return (ushort_t)r;
}

#define NT   1024
#define KIN  3072
#define KS   8      // feat GEMM K-splits (K=384 each, 6 iters of 64)

// ---------------- prep: weight transposes + bias2 init (tiny) ----------------
__global__ __launch_bounds__(256) void prep_kernel(
    const float* __restrict__ wx, const float* __restrict__ wh,
    const float* __restrict__ ow, const float* __restrict__ eb,
    ushort_t* __restrict__ wxT, float* __restrict__ whTf,
    ushort_t* __restrict__ owT, float* __restrict__ bias2)
{
  const int total = 65536 + 65536 + 16384 + 128;
  for (int i = blockIdx.x * blockDim.x + threadIdx.x; i < total;
       i += gridDim.x * blockDim.x) {
    int j = i;
    if (j < 65536) { int n = j >> 7, k = j & 127; wxT[j] = f2b(wx[k * 512 + n]); continue; }
    j -= 65536;
    if (j < 65536) { int n = j >> 7, k = j & 127; whTf[j] = wh[k * 512 + n]; continue; }
    j -= 65536;
    if (j < 16384) { int n = j >> 7, k = j & 127; owT[j] = f2b(ow[k * 128 + n]); continue; }
    j -= 16384;
    bias2[j] = eb[j];
  }
}

// ---------------- build U: fold conv into early MLP ----------------
__global__ __launch_bounds__(128) void build_u(
    const float* __restrict__ conv_w, const float* __restrict__ conv_b,
    const float* __restrict__ early_w,
    ushort_t* __restrict__ UT, float* __restrict__ bias2)
{
  __shared__ float cw[864];                      // [kh][kw][c][f]
  const int tid = threadIdx.x;                   // = o
  const int p = blockIdx.x;                      // input pixel (h',w')
  for (int i = tid; i < 864; i += 128) cw[i] = conv_w[i];
  __syncthreads();
  const int hp = p >> 5, wp = p & 31;
  float a0 = 0.f, a1 = 0.f, a2 = 0.f;
  for (int kh = 0; kh < 3; kh++) {
    int h = hp - kh + 1; if ((unsigned)h >= 32u) continue;
    for (int kw = 0; kw < 3; kw++) {
      int w = wp - kw + 1; if ((unsigned)w >= 32u) continue;
      const float* wr = early_w + ((size_t)((h * 32 + w) * 32)) * 128 + tid;
      const float* cwp = cw + (kh * 3 + kw) * 96;
      #pragma unroll 8
      for (int f = 0; f < 32; f++) {
        float wv = wr[f * 128];
        a0 += cwp[f]      * wv;
        a1 += cwp[32 + f] * wv;
        a2 += cwp[64 + f] * wv;
      }
    }
  }
  size_t ub = (size_t)tid * KIN + p * 3;
  UT[ub + 0] = f2b(a0); UT[ub + 1] = f2b(a1); UT[ub + 2] = f2b(a2);

  if (p < 32) {                                  // conv_b term (zeros here; generality)
    float part = 0.f;
    for (int pp = p * 32; pp < p * 32 + 32; pp++)
      for (int f = 0; f < 32; f++)
        part += conv_b[f] * early_w[(size_t)(pp * 32 + f) * 128 + tid];
    atomicAdd(&bias2[tid], part);
  }
}

// ---------------- feat GEMM, split-K: partial[ks] = x[:, ksK] @ U[ksK, :] ----------------
// A = x f32 (cast during staging), BT = UT bf16 [128][3072]. Tile M16 x N128 x Kchunk384.
__global__ __launch_bounds__(256) void feat_gemm(
    const float* __restrict__ x, const ushort_t* __restrict__ UT,
    float* __restrict__ partial)                 // [KS][1024][128]
{
  __shared__ short As[16 * 72];                  // rows padded +8 elems (16B)
  __shared__ short Bs[128 * 72];
  const int tid = threadIdx.x;
  const int m0 = blockIdx.x * 16;
  const int ks = blockIdx.y;
  const int wave = tid >> 6, lane = tid & 63;
  const int quad = lane >> 4, l15 = lane & 15;
  const int c0 = wave * 32;

  f32x4 acc0 = {0.f, 0.f, 0.f, 0.f};
  f32x4 acc1 = {0.f, 0.f, 0.f, 0.f};

  const int kend = ks * 384 + 384;
  for (int k0 = ks * 384; k0 < kend; k0 += 64) {
    __syncthreads();
    for (int s = tid; s < 1152; s += 256) {
      if (s < 128) {                             // A: f32 -> bf16 on the fly
        int row = s >> 3, t8 = s & 7;
        const float4* g = (const float4*)(x + (size_t)(m0 + row) * KIN + k0 + t8 * 8);
        float4 f0 = g[0], f1 = g[1];
        ushort_t tmp[8] = {f2b(f0.x), f2b(f0.y), f2b(f0.z), f2b(f0.w),
                           f2b(f1.x), f2b(f1.y), f2b(f1.z), f2b(f1.w)};
        *(uint4*)&As[row * 72 + t8 * 8] = *(const uint4*)tmp;
      } else {
        int s2 = s - 128;
        int row = s2 >> 3, t8 = s2 & 7;
        const uint4* g = (const uint4*)(UT + (size_t)row * KIN + k0 + t8 * 8);
        *(uint4*)&Bs[row * 72 + t8 * 8] = *g;
      }
    }
    __syncthreads();
    #pragma unroll
    for (int kk = 0; kk < 2; kk++) {
      int ko = kk * 32 + quad * 8;
      bf16x8 a  = *(const bf16x8*)&As[l15 * 72 + ko];
      bf16x8 b0 = *(const bf16x8*)&Bs[(c0 + l15) * 72 + ko];
      bf16x8 b1 = *(const bf16x8*)&Bs[(c0 + 16 + l15) * 72 + ko];
      acc0 = __builtin_amdgcn_mfma_f32_16x16x32_bf16(a, b0, acc0, 0, 0, 0);
      acc1 = __builtin_amdgcn_mfma_f32_16x16x32_bf16(a, b1, acc1, 0, 0, 0);
    }
  }
  #pragma unroll
  for (int r = 0; r < 4; r++) {
    int m = m0 + quad * 4 + r;
    size_t base = ((size_t)ks * 1024 + m) * 128;
    partial[base + c0 + l15]      = acc0[r];
    partial[base + c0 + 16 + l15] = acc1[r];
  }
}

// ---------------- reduce partials + bias + relu + cast ----------------
__global__ __launch_bounds__(256) void reduce_feat(
    const float* __restrict__ partial, const float* __restrict__ bias2,
    ushort_t* __restrict__ featb)
{
  int i = blockIdx.x * 256 + threadIdx.x;        // 131072
  float s = bias2[i & 127];
  #pragma unroll
  for (int ks = 0; ks < KS; ks++) s += partial[(size_t)ks * 131072 + i];
  featb[i] = f2b(fmaxf(s, 0.f));
}

// ---------------- K=128 single-shot GEMM: out = act(A @ BT^T + bias) ----------------
// tile M16 x N64, 2 waves (each 2 col-subtiles of 16)
__global__ __launch_bounds__(128) void gemm_k128(
    const ushort_t* __restrict__ A, const ushort_t* __restrict__ BT,
    const float* __restrict__ bias,
    float* __restrict__ outf, ushort_t* __restrict__ outb,
    int N, int relu)
{
  __shared__ short As[16 * 136];                 // 128 + 8 pad
  __shared__ short Bs[64 * 136];
  const int tid = threadIdx.x;
  const int m0 = blockIdx.x * 16;
  const int n0 = blockIdx.y * 64;
  const int wave = tid >> 6, lane = tid & 63;
  const int quad = lane >> 4, l15 = lane & 15;
  const int c0 = wave * 32;

  for (int s = tid; s < 1280; s += 128) {
    int row = s >> 4, t8 = s & 15;
    if (s < 256) {
      const uint4* g = (const uint4*)(A + (size_t)(m0 + row) * 128 + t8 * 8);
      *(uint4*)&As[row * 136 + t8 * 8] = *g;
    } else {
      int r2 = row - 16;
      const uint4* g = (const uint4*)(BT + (size_t)(n0 + r2) * 128 + t8 * 8);
      *(uint4*)&Bs[r2 * 136 + t8 * 8] = *g;
    }
  }
  __syncthreads();

  f32x4 acc0 = {0.f, 0.f, 0.f, 0.f};
  f32x4 acc1 = {0.f, 0.f, 0.f, 0.f};
  #pragma unroll
  for (int kk = 0; kk < 4; kk++) {
    int ko = kk * 32 + quad * 8;
    bf16x8 a  = *(const bf16x8*)&As[l15 * 136 + ko];
    bf16x8 b0 = *(const bf16x8*)&Bs[(c0 + l15) * 136 + ko];
    bf16x8 b1 = *(const bf16x8*)&Bs[(c0 + 16 + l15) * 136 + ko];
    acc0 = __builtin_amdgcn_mfma_f32_16x16x32_bf16(a, b0, acc0, 0, 0, 0);
    acc1 = __builtin_amdgcn_mfma_f32_16x16x32_bf16(a, b1, acc1, 0, 0, 0);
  }
  #pragma unroll
  for (int r = 0; r < 4; r++) {
    int m = m0 + quad * 4 + r;
    int n1 = n0 + c0 + l15, n2 = n1 + 16;
    float v1 = acc0[r] + bias[n1];
    float v2 = acc1[r] + bias[n2];
    if (relu) { v1 = fmaxf(v1, 0.f); v2 = fmaxf(v2, 0.f); }
    size_t o1 = (size_t)m * N + n1, o2 = (size_t)m * N + n2;
    if (outf) { outf[o1] = v1; outf[o2] = v2; }
    if (outb) { outb[o1] = f2b(v1); outb[o2] = f2b(v2); }
  }
}

// ---------------- segment-parallel LSTM ----------------
__device__ __forceinline__ float fsig(float x) {
  return 1.f / (1.f + exp2f(-1.44269504f * x));
}
__device__ __forceinline__ float ftanh(float x) {
  float e = exp2f(2.885390082f * x);
  return 1.f - 2.f / (e + 1.f);
}
__device__ __forceinline__ int nth_bit(unsigned long long m0, unsigned long long m1, int i) {
  int c0 = __popcll(m0);
  if (i < c0) {
    unsigned long long m = m0;
    for (int k = 0; k < i; k++) m &= m - 1;
    return __ffsll((long long)m) - 1;
  }
  i -= c0;
  unsigned long long m = m1;
  for (int k = 0; k < i; k++) m &= m - 1;
  return 64 + __ffsll((long long)m) - 1;
}

__global__ __launch_bounds__(512, 2) void lstm_scan(
    const int* __restrict__ done, const float* __restrict__ zx,
    const float* __restrict__ whTf, ushort_t* __restrict__ hsb,
    float* __restrict__ dout)
{
  __shared__ float z_s[512];
  __shared__ float h_s[128];
  __shared__ float c_s[128];
  __shared__ unsigned long long masks[16];
  const int tid = threadIdx.x;

  float w[128];                                  // Wh[:, tid] in VGPRs
  {
    const float4* wp = (const float4*)(whTf + (size_t)tid * 128);
    #pragma unroll
    for (int o = 0; o < 32; o++) {
      float4 v = wp[o];
      w[4*o+0] = v.x; w[4*o+1] = v.y; w[4*o+2] = v.z; w[4*o+3] = v.w;
    }
  }

  for (int n = 0; n < 8; n++) {
    bool flag = false;
    if (tid < 128) flag = (tid == 0) || (done[n * 128 + tid] != 0);
    unsigned long long m = __ballot(flag);
    if (tid == 0)  masks[2*n]     = m;
    if (tid == 64) masks[2*n + 1] = m;
  }
  __syncthreads();

  int total = 0;
  #pragma unroll
  for (int n = 0; n < 8; n++)
    total += __popcll(masks[2*n]) + __popcll(masks[2*n+1]);

  for (int g = blockIdx.x; g < total; g += gridDim.x) {
    int i = g, n = 0, cn = 0;
    for (; n < 8; n++) {
      cn = __popcll(masks[2*n]) + __popcll(masks[2*n+1]);
      if (i < cn) break;
      i -= cn;
    }
    int t0 = nth_bit(masks[2*n], masks[2*n+1], i);
    int t1 = (i + 1 < cn) ? nth_bit(masks[2*n], masks[2*n+1], i + 1) : 128;

    if (tid < 128) { h_s[tid] = 0.f; c_s[tid] = 0.f; }
    __syncthreads();

    float zval = zx[((size_t)n * 128 + t0) * 512 + tid];
    for (int t = t0; t < t1; t++) {
      float znext = 0.f;
      if (t + 1 < t1) znext = zx[((size_t)n * 128 + t + 1) * 512 + tid];  // prefetch
      float a0 = 0.f, a1 = 0.f, a2 = 0.f, a3 = 0.f;
      #pragma unroll
      for (int o = 0; o < 32; o++) {
        float4 hv = *(const float4*)&h_s[4 * o];
        a0 += w[4*o+0] * hv.x;
        a1 += w[4*o+1] * hv.y;
        a2 += w[4*o+2] * hv.z;
        a3 += w[4*o+3] * hv.w;
      }
      z_s[tid] = zval + (a0 + a1) + (a2 + a3);
      __syncthreads();
      if (tid < 128) {
        float ig = fsig(z_s[tid]);
        float fg = fsig(z_s[tid + 128]);
        float gg = ftanh(z_s[tid + 256]);
        float og = fsig(z_s[tid + 384]);
        float c = fg * c_s[tid] + ig * gg;
        float hn = og * ftanh(c);
        c_s[tid] = c; h_s[tid] = hn;
        hsb[((size_t)n * 128 + t) * 128 + tid] = f2b(hn);
        if (t == 127) {
          dout[n * 128 + tid] = c;
          dout[1024 + n * 128 + tid] = hn;
        }
      }
      __syncthreads();
      zval = znext;
    }
  }
}

// ---------------- launch ----------------
extern "C" void kernel_launch(void* const* d_in, const int* in_sizes, int n_in,
                              void* d_out, int out_size, void* d_ws, size_t ws_size,
                              hipStream_t stream) {
  const float* x       = (const float*)d_in[0];
  const int*   done    = (const int*)  d_in[1];
  const float* conv_w  = (const float*)d_in[2];
  const float* conv_b  = (const float*)d_in[3];
  const float* early_w = (const float*)d_in[4];
  const float* early_b = (const float*)d_in[5];
  const float* lstm_wx = (const float*)d_in[6];
  const float* lstm_wh = (const float*)d_in[7];
  const float* lstm_b  = (const float*)d_in[8];
  const float* out_w   = (const float*)d_in[9];
  const float* out_b   = (const float*)d_in[10];
  float* dout = (float*)d_out;                   // [c_fin 1024][h_fin 1024][y 131072]

  char* ws = (char*)d_ws;
  float*    partial = (float*)   (ws + 0);        // [8][1024][128] f32   4 MB
  ushort_t* UT      = (ushort_t*)(ws + 4194304);  // [128][3072] bf16
  ushort_t* featb   = (ushort_t*)(ws + 4980736);  // [1024][128] bf16
  float*    zx      = (float*)   (ws + 5242880);  // [1024][512] f32
  ushort_t* wxT     = (ushort_t*)(ws + 7340032);  // [512][128] bf16
  float*    whTf    = (float*)   (ws + 7471104);  // [512][128] f32
  ushort_t* owT     = (ushort_t*)(ws + 7733248);  // [128][128] bf16
  ushort_t* hsb     = (ushort_t*)(ws + 7766016);  // [1024][128] bf16
  float*    bias2   = (float*)   (ws + 8028160);  // [128] f32

  prep_kernel<<<144, 256, 0, stream>>>(lstm_wx, lstm_wh, out_w, early_b,
                                       wxT, whTf, owT, bias2);
  build_u<<<1024, 128, 0, stream>>>(conv_w, conv_b, early_w, UT, bias2);
  // feat partials: [1024,3072]@[3072,128], split-K x8
  feat_gemm<<<dim3(64, KS), 256, 0, stream>>>(x, UT, partial);
  reduce_feat<<<512, 256, 0, stream>>>(partial, bias2, featb);
  // zx = feat @ Wx + lstm_b    [1024,128]@[128,512]
  gemm_k128<<<dim3(64, 8), 128, 0, stream>>>(featb, wxT, lstm_b, zx, nullptr, 512, 0);
  // LSTM
  lstm_scan<<<128, 512, 0, stream>>>(done, zx, whTf, hsb, dout);
  // y = relu(hs @ out_w + out_b)  [1024,128]@[128,128]
  gemm_k128<<<dim3(64, 2), 128, 0, stream>>>(hsb, owT, out_b, dout + 2048, nullptr, 128, 1);
}

// Round 3
// 154.599 us; speedup vs baseline: 1.8816x; 1.2120x over previous
//
#include <hip/hip_runtime.h>

// conv(3x3,C3->F32) -> earlyMLP(32768->128) -> reset-masked LSTM(128) -> outMLP(128->128)
// R2: lstm_scan was 46us: w[128] f32 spilled (VGPR_Count=120 < 128). Now Wh kept as
//     packed-f16 pairs in 32 VGPRs, matvec via v_dot2_f32_f16 (2 MAC/inst). Also
//     build_u's serial conv_b tail gated behind a conv_b!=0 check (all-zero here).

typedef unsigned short ushort_t;
typedef short bf16x8 __attribute__((ext_vector_type(8)));
typedef float f32x4 __attribute__((ext_vector_type(4)));
typedef _Float16 h2 __attribute__((ext_vector_type(2)));

__device__ __forceinline__ ushort_t f2b(float f) {
  unsigned int u = __float_as_uint(f);
  unsigned int r = (u + 0x7fffu + ((u >> 16) & 1u)) >> 16;  // RNE
  return (ushort_t)r;
}
__device__ __forceinline__ unsigned pack_h2(float a, float b) {
  union { _Float16 h[2]; unsigned u; } v;
  v.h[0] = (_Float16)a; v.h[1] = (_Float16)b; return v.u;
}

#define NT   1024
#define KIN  3072
#define KS   8      // feat GEMM K-splits (K=384 each, 6 iters of 64)

// ---------------- prep: weight transposes + bias2 init (tiny) ----------------
__global__ __launch_bounds__(256) void prep_kernel(
    const float* __restrict__ wx, const float* __restrict__ wh,
    const float* __restrict__ ow, const float* __restrict__ eb,
    ushort_t* __restrict__ wxT, unsigned* __restrict__ whT16,
    ushort_t* __restrict__ owT, float* __restrict__ bias2)
{
  const int total = 65536 + 32768 + 16384 + 128;
  for (int i = blockIdx.x * blockDim.x + threadIdx.x; i < total;
       i += gridDim.x * blockDim.x) {
    int j = i;
    if (j < 65536) { int n = j >> 7, k = j & 127; wxT[j] = f2b(wx[k * 512 + n]); continue; }
    j -= 65536;
    if (j < 32768) {                             // packed f16 pairs of Wh[:,col]
      int col = j >> 6, k2 = j & 63;
      whT16[j] = pack_h2(wh[(2 * k2) * 512 + col], wh[(2 * k2 + 1) * 512 + col]);
      continue;
    }
    j -= 32768;
    if (j < 16384) { int n = j >> 7, k = j & 127; owT[j] = f2b(ow[k * 128 + n]); continue; }
    j -= 16384;
    bias2[j] = eb[j];
  }
}

// ---------------- build U: fold conv into early MLP ----------------
__global__ __launch_bounds__(128) void build_u(
    const float* __restrict__ conv_w, const float* __restrict__ conv_b,
    const float* __restrict__ early_w,
    ushort_t* __restrict__ UT, float* __restrict__ bias2)
{
  __shared__ float cw[864];                      // [kh][kw][c][f]
  const int tid = threadIdx.x;                   // = o
  const int p = blockIdx.x;                      // input pixel (h',w')
  for (int i = tid; i < 864; i += 128) cw[i] = conv_w[i];
  __syncthreads();
  const int hp = p >> 5, wp = p & 31;
  float a0 = 0.f, a1 = 0.f, a2 = 0.f;
  for (int kh = 0; kh < 3; kh++) {
    int h = hp - kh + 1; if ((unsigned)h >= 32u) continue;
    for (int kw = 0; kw < 3; kw++) {
      int w = wp - kw + 1; if ((unsigned)w >= 32u) continue;
      const float* wr = early_w + ((size_t)((h * 32 + w) * 32)) * 128 + tid;
      const float* cwp = cw + (kh * 3 + kw) * 96;
      #pragma unroll 8
      for (int f = 0; f < 32; f++) {
        float wv = wr[f * 128];
        a0 += cwp[f]      * wv;
        a1 += cwp[32 + f] * wv;
        a2 += cwp[64 + f] * wv;
      }
    }
  }
  size_t ub = (size_t)tid * KIN + p * 3;
  UT[ub + 0] = f2b(a0); UT[ub + 1] = f2b(a1); UT[ub + 2] = f2b(a2);

  // conv_b fold (zeros in this problem -> skipped by uniform branch)
  float cbs = 0.f;
  #pragma unroll 8
  for (int f = 0; f < 32; f++) cbs += __builtin_fabsf(conv_b[f]);
  if (cbs != 0.f && p < 32) {
    float part = 0.f;
    for (int pp = p * 32; pp < p * 32 + 32; pp++)
      for (int f = 0; f < 32; f++)
        part += conv_b[f] * early_w[(size_t)(pp * 32 + f) * 128 + tid];
    atomicAdd(&bias2[tid], part);
  }
}

// ---------------- feat GEMM, split-K: partial[ks] = x[:, ksK] @ U[ksK, :] ----------------
__global__ __launch_bounds__(256) void feat_gemm(
    const float* __restrict__ x, const ushort_t* __restrict__ UT,
    float* __restrict__ partial)                 // [KS][1024][128]
{
  __shared__ short As[16 * 72];
  __shared__ short Bs[128 * 72];
  const int tid = threadIdx.x;
  const int m0 = blockIdx.x * 16;
  const int ks = blockIdx.y;
  const int wave = tid >> 6, lane = tid & 63;
  const int quad = lane >> 4, l15 = lane & 15;
  const int c0 = wave * 32;

  f32x4 acc0 = {0.f, 0.f, 0.f, 0.f};
  f32x4 acc1 = {0.f, 0.f, 0.f, 0.f};

  const int kend = ks * 384 + 384;
  for (int k0 = ks * 384; k0 < kend; k0 += 64) {
    __syncthreads();
    for (int s = tid; s < 1152; s += 256) {
      if (s < 128) {                             // A: f32 -> bf16 on the fly
        int row = s >> 3, t8 = s & 7;
        const float4* g = (const float4*)(x + (size_t)(m0 + row) * KIN + k0 + t8 * 8);
        float4 f0 = g[0], f1 = g[1];
        ushort_t tmp[8] = {f2b(f0.x), f2b(f0.y), f2b(f0.z), f2b(f0.w),
                           f2b(f1.x), f2b(f1.y), f2b(f1.z), f2b(f1.w)};
        *(uint4*)&As[row * 72 + t8 * 8] = *(const uint4*)tmp;
      } else {
        int s2 = s - 128;
        int row = s2 >> 3, t8 = s2 & 7;
        const uint4* g = (const uint4*)(UT + (size_t)row * KIN + k0 + t8 * 8);
        *(uint4*)&Bs[row * 72 + t8 * 8] = *g;
      }
    }
    __syncthreads();
    #pragma unroll
    for (int kk = 0; kk < 2; kk++) {
      int ko = kk * 32 + quad * 8;
      bf16x8 a  = *(const bf16x8*)&As[l15 * 72 + ko];
      bf16x8 b0 = *(const bf16x8*)&Bs[(c0 + l15) * 72 + ko];
      bf16x8 b1 = *(const bf16x8*)&Bs[(c0 + 16 + l15) * 72 + ko];
      acc0 = __builtin_amdgcn_mfma_f32_16x16x32_bf16(a, b0, acc0, 0, 0, 0);
      acc1 = __builtin_amdgcn_mfma_f32_16x16x32_bf16(a, b1, acc1, 0, 0, 0);
    }
  }
  #pragma unroll
  for (int r = 0; r < 4; r++) {
    int m = m0 + quad * 4 + r;
    size_t base = ((size_t)ks * 1024 + m) * 128;
    partial[base + c0 + l15]      = acc0[r];
    partial[base + c0 + 16 + l15] = acc1[r];
  }
}

// ---------------- reduce partials + bias + relu + cast ----------------
__global__ __launch_bounds__(256) void reduce_feat(
    const float* __restrict__ partial, const float* __restrict__ bias2,
    ushort_t* __restrict__ featb)
{
  int i = blockIdx.x * 256 + threadIdx.x;        // 131072
  float s = bias2[i & 127];
  #pragma unroll
  for (int ks = 0; ks < KS; ks++) s += partial[(size_t)ks * 131072 + i];
  featb[i] = f2b(fmaxf(s, 0.f));
}

// ---------------- K=128 single-shot GEMM: out = act(A @ BT^T + bias) ----------------
__global__ __launch_bounds__(128) void gemm_k128(
    const ushort_t* __restrict__ A, const ushort_t* __restrict__ BT,
    const float* __restrict__ bias,
    float* __restrict__ outf, ushort_t* __restrict__ outb,
    int N, int relu)
{
  __shared__ short As[16 * 136];
  __shared__ short Bs[64 * 136];
  const int tid = threadIdx.x;
  const int m0 = blockIdx.x * 16;
  const int n0 = blockIdx.y * 64;
  const int wave = tid >> 6, lane = tid & 63;
  const int quad = lane >> 4, l15 = lane & 15;
  const int c0 = wave * 32;

  for (int s = tid; s < 1280; s += 128) {
    int row = s >> 4, t8 = s & 15;
    if (s < 256) {
      const uint4* g = (const uint4*)(A + (size_t)(m0 + row) * 128 + t8 * 8);
      *(uint4*)&As[row * 136 + t8 * 8] = *g;
    } else {
      int r2 = row - 16;
      const uint4* g = (const uint4*)(BT + (size_t)(n0 + r2) * 128 + t8 * 8);
      *(uint4*)&Bs[r2 * 136 + t8 * 8] = *g;
    }
  }
  __syncthreads();

  f32x4 acc0 = {0.f, 0.f, 0.f, 0.f};
  f32x4 acc1 = {0.f, 0.f, 0.f, 0.f};
  #pragma unroll
  for (int kk = 0; kk < 4; kk++) {
    int ko = kk * 32 + quad * 8;
    bf16x8 a  = *(const bf16x8*)&As[l15 * 136 + ko];
    bf16x8 b0 = *(const bf16x8*)&Bs[(c0 + l15) * 136 + ko];
    bf16x8 b1 = *(const bf16x8*)&Bs[(c0 + 16 + l15) * 136 + ko];
    acc0 = __builtin_amdgcn_mfma_f32_16x16x32_bf16(a, b0, acc0, 0, 0, 0);
    acc1 = __builtin_amdgcn_mfma_f32_16x16x32_bf16(a, b1, acc1, 0, 0, 0);
  }
  #pragma unroll
  for (int r = 0; r < 4; r++) {
    int m = m0 + quad * 4 + r;
    int n1 = n0 + c0 + l15, n2 = n1 + 16;
    float v1 = acc0[r] + bias[n1];
    float v2 = acc1[r] + bias[n2];
    if (relu) { v1 = fmaxf(v1, 0.f); v2 = fmaxf(v2, 0.f); }
    size_t o1 = (size_t)m * N + n1, o2 = (size_t)m * N + n2;
    if (outf) { outf[o1] = v1; outf[o2] = v2; }
    if (outb) { outb[o1] = f2b(v1); outb[o2] = f2b(v2); }
  }
}

// ---------------- segment-parallel LSTM (f16 dot2, 32-VGPR weight column) ----------------
__device__ __forceinline__ float fsig(float x) {
  return 1.f / (1.f + exp2f(-1.44269504f * x));
}
__device__ __forceinline__ float ftanh(float x) {
  float e = exp2f(2.885390082f * x);
  return 1.f - 2.f / (e + 1.f);
}
__device__ __forceinline__ int nth_bit(unsigned long long m0, unsigned long long m1, int i) {
  int c0 = __popcll(m0);
  if (i < c0) {
    unsigned long long m = m0;
    for (int k = 0; k < i; k++) m &= m - 1;
    return __ffsll((long long)m) - 1;
  }
  i -= c0;
  unsigned long long m = m1;
  for (int k = 0; k < i; k++) m &= m - 1;
  return 64 + __ffsll((long long)m) - 1;
}

// 512 threads: thread j owns gate-column j; Wh[:,j] packed f16 in 16 uint4 (32 VGPRs).
__global__ __launch_bounds__(512, 2) void lstm_scan(
    const int* __restrict__ done, const float* __restrict__ zx,
    const unsigned* __restrict__ whT16, ushort_t* __restrict__ hsb,
    float* __restrict__ dout)
{
  __shared__ float z_s[512];
  __shared__ _Float16 h16_s[128];                // h packed f16, read as float4 (broadcast)
  __shared__ float c_s[128];
  __shared__ unsigned long long masks[16];
  const int tid = threadIdx.x;

  uint4 w4[16];                                  // Wh[:, tid] as 64 half2 pairs
  {
    const uint4* wp = (const uint4*)(whT16 + (size_t)tid * 64);
    #pragma unroll
    for (int i = 0; i < 16; i++) w4[i] = wp[i];
  }
  const h2* wv = (const h2*)w4;

  for (int n = 0; n < 8; n++) {
    bool flag = false;
    if (tid < 128) flag = (tid == 0) || (done[n * 128 + tid] != 0);
    unsigned long long m = __ballot(flag);
    if (tid == 0)  masks[2*n]     = m;
    if (tid == 64) masks[2*n + 1] = m;
  }
  __syncthreads();

  int total = 0;
  #pragma unroll
  for (int n = 0; n < 8; n++)
    total += __popcll(masks[2*n]) + __popcll(masks[2*n+1]);

  for (int g = blockIdx.x; g < total; g += gridDim.x) {
    int i = g, n = 0, cn = 0;
    for (; n < 8; n++) {
      cn = __popcll(masks[2*n]) + __popcll(masks[2*n+1]);
      if (i < cn) break;
      i -= cn;
    }
    int t0 = nth_bit(masks[2*n], masks[2*n+1], i);
    int t1 = (i + 1 < cn) ? nth_bit(masks[2*n], masks[2*n+1], i + 1) : 128;

    if (tid < 128) { ((ushort_t*)h16_s)[tid] = 0; c_s[tid] = 0.f; }
    __syncthreads();

    float zval = zx[((size_t)n * 128 + t0) * 512 + tid];
    for (int t = t0; t < t1; t++) {
      float znext = 0.f;
      if (t + 1 < t1) znext = zx[((size_t)n * 128 + t + 1) * 512 + tid];  // prefetch
      float a0 = 0.f, a1 = 0.f, a2 = 0.f, a3 = 0.f;
      const float4* hp = (const float4*)h16_s;
      #pragma unroll
      for (int q = 0; q < 16; q++) {
        float4 hb = hp[q];                       // 8 f16 = 4 pairs, wave-broadcast
        const h2* hh = (const h2*)&hb;
        a0 = __builtin_amdgcn_fdot2(wv[4*q+0], hh[0], a0, false);
        a1 = __builtin_amdgcn_fdot2(wv[4*q+1], hh[1], a1, false);
        a2 = __builtin_amdgcn_fdot2(wv[4*q+2], hh[2], a2, false);
        a3 = __builtin_amdgcn_fdot2(wv[4*q+3], hh[3], a3, false);
      }
      z_s[tid] = zval + (a0 + a1) + (a2 + a3);
      __syncthreads();
      if (tid < 128) {
        float ig = fsig(z_s[tid]);
        float fg = fsig(z_s[tid + 128]);
        float gg = ftanh(z_s[tid + 256]);
        float og = fsig(z_s[tid + 384]);
        float c = fg * c_s[tid] + ig * gg;
        float hn = og * ftanh(c);
        c_s[tid] = c;
        h16_s[tid] = (_Float16)hn;
        hsb[((size_t)n * 128 + t) * 128 + tid] = f2b(hn);
        if (t == 127) {
          dout[n * 128 + tid] = c;
          dout[1024 + n * 128 + tid] = hn;
        }
      }
      __syncthreads();
      zval = znext;
    }
  }
}

// ---------------- launch ----------------
extern "C" void kernel_launch(void* const* d_in, const int* in_sizes, int n_in,
                              void* d_out, int out_size, void* d_ws, size_t ws_size,
                              hipStream_t stream) {
  const float* x       = (const float*)d_in[0];
  const int*   done    = (const int*)  d_in[1];
  const float* conv_w  = (const float*)d_in[2];
  const float* conv_b  = (const float*)d_in[3];
  const float* early_w = (const float*)d_in[4];
  const float* early_b = (const float*)d_in[5];
  const float* lstm_wx = (const float*)d_in[6];
  const float* lstm_wh = (const float*)d_in[7];
  const float* lstm_b  = (const float*)d_in[8];
  const float* out_w   = (const float*)d_in[9];
  const float* out_b   = (const float*)d_in[10];
  float* dout = (float*)d_out;                   // [c_fin 1024][h_fin 1024][y 131072]

  char* ws = (char*)d_ws;
  float*    partial = (float*)   (ws + 0);        // [8][1024][128] f32   4 MB
  ushort_t* UT      = (ushort_t*)(ws + 4194304);  // [128][3072] bf16
  ushort_t* featb   = (ushort_t*)(ws + 4980736);  // [1024][128] bf16
  float*    zx      = (float*)   (ws + 5242880);  // [1024][512] f32
  ushort_t* wxT     = (ushort_t*)(ws + 7340032);  // [512][128] bf16
  unsigned* whT16   = (unsigned*)(ws + 7471104);  // [512][64] packed f16x2
  ushort_t* owT     = (ushort_t*)(ws + 7733248);  // [128][128] bf16
  ushort_t* hsb     = (ushort_t*)(ws + 7766016);  // [1024][128] bf16
  float*    bias2   = (float*)   (ws + 8028160);  // [128] f32

  prep_kernel<<<120, 256, 0, stream>>>(lstm_wx, lstm_wh, out_w, early_b,
                                       wxT, whT16, owT, bias2);
  build_u<<<1024, 128, 0, stream>>>(conv_w, conv_b, early_w, UT, bias2);
  // feat partials: [1024,3072]@[3072,128], split-K x8
  feat_gemm<<<dim3(64, KS), 256, 0, stream>>>(x, UT, partial);
  reduce_feat<<<512, 256, 0, stream>>>(partial, bias2, featb);
  // zx = feat @ Wx + lstm_b    [1024,128]@[128,512]
  gemm_k128<<<dim3(64, 8), 128, 0, stream>>>(featb, wxT, lstm_b, zx, nullptr, 512, 0);
  // LSTM
  lstm_scan<<<512, 512, 0, stream>>>(done, zx, whT16, hsb, dout);
  // y = relu(hs @ out_w + out_b)  [1024,128]@[128,128]
  gemm_k128<<<dim3(64, 2), 128, 0, stream>>>(hsb, owT, out_b, dout + 2048, nullptr, 128, 1);
}